// Round 1
// baseline (656.758 us; speedup 1.0000x reference)
//
#include <hip/hip_runtime.h>
#include <hip/hip_bf16.h>

typedef unsigned short u16_t;
typedef unsigned int   u32_t;

#define B_ROWS  16384
#define D_IN    1024
#define D_OUT   512
#define NEXP    16
#define EPSF    2.2204460492503131e-16f

using short8  = __attribute__((ext_vector_type(8))) short;
using floatx4 = __attribute__((ext_vector_type(4))) float;

__device__ __forceinline__ u16_t f2bf(float f) {
    u32_t u = __float_as_uint(f);
    u += 0x7fffu + ((u >> 16) & 1u);        // round-to-nearest-even
    return (u16_t)(u >> 16);
}

// ---------------------------------------------------------------------------
// Router: one wave per row. Lane (e = lane&15, q = lane>>4) accumulates a
// quarter of the f64 dot product for expert e; xor-shuffle reduce; top-2 +
// softmax gates; append (row<<1|slot, gate) to per-expert lists via atomics.
// f64 so expert selection matches the high-precision np reference.
// ---------------------------------------------------------------------------
__global__ __launch_bounds__(256) void router_kernel(
        const float* __restrict__ x, const float* __restrict__ wr,
        int* __restrict__ counts, int* __restrict__ rowlist,
        float* __restrict__ gatelist) {
    int wave = threadIdx.x >> 6;
    int lane = threadIdx.x & 63;
    int b = blockIdx.x * 4 + wave;
    int e = lane & 15, q = lane >> 4;
    const float* xb = x + (size_t)b * D_IN;

    double acc = 0.0;
    #pragma unroll 8
    for (int i = 0; i < 256; ++i) {
        int d = q * 256 + i;
        acc += (double)xb[d] * (double)wr[d * NEXP + e];
    }
    acc += __shfl_xor(acc, 16);
    acc += __shfl_xor(acc, 32);
    // lanes 0..15 now hold logits[e]; broadcast-scan for top-2 (all lanes)
    int i1 = -1; double v1 = -1e300;
    for (int ee = 0; ee < NEXP; ++ee) {
        double t = __shfl(acc, ee);
        if (t > v1) { v1 = t; i1 = ee; }
    }
    int i2 = -1; double v2 = -1e300;
    for (int ee = 0; ee < NEXP; ++ee) {
        double t = __shfl(acc, ee);
        if (ee != i1 && t > v2) { v2 = t; i2 = ee; }
    }
    if (lane == 0) {
        double ed = exp(v2 - v1);          // <= 1
        double s = 1.0 + ed;
        float g1 = (float)(1.0 / s);
        float g2 = (float)(ed / s);
        int p1 = atomicAdd(&counts[i1], 1);
        rowlist[i1 * B_ROWS + p1] = (b << 1);
        gatelist[i1 * B_ROWS + p1] = g1;
        int p2 = atomicAdd(&counts[i2], 1);
        rowlist[i2 * B_ROWS + p2] = (b << 1) | 1;
        gatelist[i2 * B_ROWS + p2] = g2;
    }
}

// ---------------------------------------------------------------------------
// Grouped expert GEMM, 128x128 tile, BK=32, bf16 MFMA 16x16x32, 4 waves in
// 2x2; epilogue applies gate*exp and stores per-slot (contrib path) or
// atomicAdds into out (fallback).
// ---------------------------------------------------------------------------
template<bool USE_CONTRIB>
__global__ __launch_bounds__(256) void moe_gemm(
        const float* __restrict__ x, const float* __restrict__ w,
        const int* __restrict__ counts, const int* __restrict__ rowlist,
        const float* __restrict__ gatelist,
        float* __restrict__ out, float* __restrict__ contrib) {
    int e = blockIdx.z;
    int n_e = counts[e];
    int ty = blockIdx.y;
    if (ty * 128 >= n_e) return;
    int n0 = blockIdx.x * 128;

    __shared__ u16_t Ash[128][40];   // [m][k] bf16, pad 32->40
    __shared__ u32_t Bsh[16][132];   // [k-pair][n] packed bf16x2, pad 128->132
    __shared__ int   rid_sh[128];
    __shared__ float gt_sh[128];

    int t = threadIdx.x;
    if (t < 128) {
        int gi = ty * 128 + t;
        int v = 0; float g = 0.f;
        if (gi < n_e) { v = rowlist[e * B_ROWS + gi]; g = gatelist[e * B_ROWS + gi]; }
        rid_sh[t] = v; gt_sh[t] = g;
    }
    __syncthreads();

    // staging assignments
    int ar = t >> 1, ah = t & 1;                 // A: row, k-half
    const float* xptr = x + (size_t)(rid_sh[ar] >> 1) * D_IN + ah * 16;
    int bkp = t >> 4, bng = t & 15;              // B: k-pair, n-group of 8
    const float* wptr = w + (size_t)e * (D_IN * D_OUT)
                          + (size_t)(2 * bkp) * D_OUT + n0 + bng * 8;

    int lane = t & 63, wv = t >> 6;
    int wm = wv >> 1, wn = wv & 1;
    int lm = lane & 15, q = lane >> 4;

    floatx4 acc[4][4];
    #pragma unroll
    for (int mi = 0; mi < 4; ++mi)
        #pragma unroll
        for (int ni = 0; ni < 4; ++ni)
            acc[mi][ni] = (floatx4){0.f, 0.f, 0.f, 0.f};

    for (int it = 0; it < D_IN / 32; ++it) {
        float4 av0 = *(const float4*)(xptr + 0);
        float4 av1 = *(const float4*)(xptr + 4);
        float4 av2 = *(const float4*)(xptr + 8);
        float4 av3 = *(const float4*)(xptr + 12);
        xptr += 32;
        float4 b0 = *(const float4*)(wptr + 0);
        float4 b1 = *(const float4*)(wptr + 4);
        float4 b2 = *(const float4*)(wptr + D_OUT);
        float4 b3 = *(const float4*)(wptr + D_OUT + 4);
        wptr += 32 * D_OUT;

        __syncthreads();   // prev iter's LDS reads done
        {
            union { u16_t us[16]; uint4 v[2]; } ap;
            float af[16] = {av0.x, av0.y, av0.z, av0.w, av1.x, av1.y, av1.z, av1.w,
                            av2.x, av2.y, av2.z, av2.w, av3.x, av3.y, av3.z, av3.w};
            #pragma unroll
            for (int j = 0; j < 16; ++j) ap.us[j] = f2bf(af[j]);
            *(uint4*)(&Ash[ar][ah * 16])     = ap.v[0];
            *(uint4*)(&Ash[ar][ah * 16 + 8]) = ap.v[1];
        }
        {
            union { u32_t up[8]; uint4 v[2]; } bp;
            bp.up[0] = (u32_t)f2bf(b0.x) | ((u32_t)f2bf(b2.x) << 16);
            bp.up[1] = (u32_t)f2bf(b0.y) | ((u32_t)f2bf(b2.y) << 16);
            bp.up[2] = (u32_t)f2bf(b0.z) | ((u32_t)f2bf(b2.z) << 16);
            bp.up[3] = (u32_t)f2bf(b0.w) | ((u32_t)f2bf(b2.w) << 16);
            bp.up[4] = (u32_t)f2bf(b1.x) | ((u32_t)f2bf(b3.x) << 16);
            bp.up[5] = (u32_t)f2bf(b1.y) | ((u32_t)f2bf(b3.y) << 16);
            bp.up[6] = (u32_t)f2bf(b1.z) | ((u32_t)f2bf(b3.z) << 16);
            bp.up[7] = (u32_t)f2bf(b1.w) | ((u32_t)f2bf(b3.w) << 16);
            *(uint4*)(&Bsh[bkp][bng * 8])     = bp.v[0];
            *(uint4*)(&Bsh[bkp][bng * 8 + 4]) = bp.v[1];
        }
        __syncthreads();

        short8 afr[4];
        #pragma unroll
        for (int mi = 0; mi < 4; ++mi)
            afr[mi] = *(const short8*)(&Ash[wm * 64 + mi * 16 + lm][q * 8]);
        short8 bfr[4];
        #pragma unroll
        for (int ni = 0; ni < 4; ++ni) {
            int nn = wn * 64 + ni * 16 + lm;
            union { uint4 u; short8 s; } cv;
            cv.u.x = Bsh[q * 4 + 0][nn];
            cv.u.y = Bsh[q * 4 + 1][nn];
            cv.u.z = Bsh[q * 4 + 2][nn];
            cv.u.w = Bsh[q * 4 + 3][nn];
            bfr[ni] = cv.s;
        }
        #pragma unroll
        for (int mi = 0; mi < 4; ++mi)
            #pragma unroll
            for (int ni = 0; ni < 4; ++ni)
                acc[mi][ni] = __builtin_amdgcn_mfma_f32_16x16x32_bf16(
                    afr[mi], bfr[ni], acc[mi][ni], 0, 0, 0);
    }

    // epilogue: C/D layout col=lane&15, row=(lane>>4)*4+reg
    #pragma unroll
    for (int mi = 0; mi < 4; ++mi) {
        int rbase = wm * 64 + mi * 16 + q * 4;
        #pragma unroll
        for (int r = 0; r < 4; ++r) {
            int row = rbase + r;
            int gi = ty * 128 + row;
            bool ok = gi < n_e;
            int v = rid_sh[row];
            float g = gt_sh[row];
            size_t orow = (size_t)(v >> 1) * D_OUT;
            #pragma unroll
            for (int ni = 0; ni < 4; ++ni) {
                int c = n0 + wn * 64 + ni * 16 + lm;
                float val = g * __expf(acc[mi][ni][r]);
                if (ok) {
                    if (USE_CONTRIB) {
                        float* dst = (v & 1) ? contrib : out;
                        dst[orow + c] = val;
                    } else {
                        atomicAdd(&out[orow + c], val);
                    }
                }
            }
        }
    }
}

// ---------------------------------------------------------------------------
// Combine: out = log(clamp(slot0 + slot1, eps))
// ---------------------------------------------------------------------------
__global__ __launch_bounds__(256) void combine_add_log(
        float* __restrict__ out, const float* __restrict__ contrib, int n4) {
    int i = blockIdx.x * blockDim.x + threadIdx.x;
    if (i >= n4) return;
    float4 a = ((const float4*)out)[i];
    float4 b = ((const float4*)contrib)[i];
    float4 r;
    float s;
    s = a.x + b.x; s = (s == 0.f) ? EPSF : s; r.x = __logf(s);
    s = a.y + b.y; s = (s == 0.f) ? EPSF : s; r.y = __logf(s);
    s = a.z + b.z; s = (s == 0.f) ? EPSF : s; r.z = __logf(s);
    s = a.w + b.w; s = (s == 0.f) ? EPSF : s; r.w = __logf(s);
    ((float4*)out)[i] = r;
}

__global__ __launch_bounds__(256) void log_inplace(float* __restrict__ out, int n4) {
    int i = blockIdx.x * blockDim.x + threadIdx.x;
    if (i >= n4) return;
    float4 a = ((float4*)out)[i];
    float4 r;
    float s;
    s = a.x; s = (s == 0.f) ? EPSF : s; r.x = __logf(s);
    s = a.y; s = (s == 0.f) ? EPSF : s; r.y = __logf(s);
    s = a.z; s = (s == 0.f) ? EPSF : s; r.z = __logf(s);
    s = a.w; s = (s == 0.f) ? EPSF : s; r.w = __logf(s);
    ((float4*)out)[i] = r;
}

extern "C" void kernel_launch(void* const* d_in, const int* in_sizes, int n_in,
                              void* d_out, int out_size, void* d_ws, size_t ws_size,
                              hipStream_t stream) {
    const float* x  = (const float*)d_in[0];
    const float* wr = (const float*)d_in[1];
    const float* we = (const float*)d_in[2];
    float* out = (float*)d_out;
    char* ws = (char*)d_ws;

    int*   counts  = (int*)ws;                                  // 64 B
    int*   rowlist = (int*)(ws + 256);                          // 1 MB
    float* gates   = (float*)(ws + 256 + (size_t)NEXP * B_ROWS * 4);  // 1 MB
    size_t cbase   = 256 + 2ull * NEXP * B_ROWS * 4;
    float* contrib = (float*)(ws + cbase);                      // 32 MB (optional)
    bool use_contrib = ws_size >= cbase + (size_t)B_ROWS * D_OUT * 4;

    hipMemsetAsync(counts, 0, 64, stream);
    router_kernel<<<B_ROWS / 4, 256, 0, stream>>>(x, wr, counts, rowlist, gates);

    dim3 g(D_OUT / 128, B_ROWS / 128, NEXP);
    int n4 = B_ROWS * D_OUT / 4;
    if (use_contrib) {
        moe_gemm<true><<<g, 256, 0, stream>>>(x, we, counts, rowlist, gates, out, contrib);
        combine_add_log<<<(n4 + 255) / 256, 256, 0, stream>>>(out, contrib, n4);
    } else {
        hipMemsetAsync(out, 0, (size_t)B_ROWS * D_OUT * 4, stream);
        moe_gemm<false><<<g, 256, 0, stream>>>(x, we, counts, rowlist, gates, out, nullptr);
        log_inplace<<<(n4 + 255) / 256, 256, 0, stream>>>(out, n4);
    }
}